// Round 2
// baseline (289.952 us; speedup 1.0000x reference)
//
#include <hip/hip_runtime.h>
#include <stdint.h>

// ResNetV1 sparse conv block, MI355X (gfx950).
// out = relu( conv(relu(conv(x,W0)), W1) + x ),  conv[n,d] = sum_k sum_c x[idx[n,k],c] * W[k,c,d]
// N=150000, K=27, C=64.
// R10 = R9 (96 us/conv) + cross-barrier A-gather pipelining (depth 1).
// Theory: latency*MLP wall. R9's __syncthreads drains vmcnt(0) every k, so the 4 random
// A-gathers per wave-iter are issued AND consumed in the same iteration: ~500cy exposed
// latency, MfmaUtil 13%. Fix (m201/HK pattern): raw s_barrier + counted vmcnt.
//   iter k invariant (outstanding vmem, oldest first): A(k)=4 loads, S(k)=2 stage ops.
//   body: issue A(k+1) [4] -> read gi(k+2) -> s_waitcnt vmcnt(4) (A(k),S(k) done;
//   A(k+1) stays in flight) -> s_barrier (all waves' stage(k) chunks landed; all waves
//   done reading buf^1) -> issue S(k+1) into buf^1 (WAR-safe) -> 8 ds_read b + 16 MFMA.
// Gather latency now spans a full iteration of block-wide compute instead of ~100cy.

typedef __attribute__((ext_vector_type(8))) short short8;
typedef __attribute__((ext_vector_type(4))) float f32x4;

#define NV 150000
#define KOFF 27

static __device__ __forceinline__ ushort f2bf(float f) {
  union { float f; uint32_t u; } v; v.f = f;
  uint32_t u = v.u;
  return (ushort)((u + 0x7fffu + ((u >> 16) & 1u)) >> 16);
}

// Fused prep: x -> bf16 (4/thread), then pack W0, W1 into B-fragment order.
// Pack map: flat = (((k*2+s)*4+ct)*64 + l)*8 + j <- W[k][c=s*32+(l>>4)*8+j][d=ct*16+(l&15)]
__global__ void prep_kernel(const float* __restrict__ x,
                            const float* __restrict__ W0,
                            const float* __restrict__ W1,
                            ushort* __restrict__ xb,
                            ushort* __restrict__ wp0,
                            ushort* __restrict__ wp1,
                            int nc4, int wtot) {
  int i = blockIdx.x * 256 + threadIdx.x;
  if (i < nc4) {
    float4 v = ((const float4*)x)[i];
    ushort4 o;
    o.x = f2bf(v.x); o.y = f2bf(v.y); o.z = f2bf(v.z); o.w = f2bf(v.w);
    ((ushort4*)xb)[i] = o;
    return;
  }
  int o = i - nc4;
  const float* W = W0;
  ushort* wp = wp0;
  if (o >= wtot) { o -= wtot; W = W1; wp = wp1; }
  if (o >= wtot) return;
  int j  = o & 7;
  int l  = (o >> 3) & 63;
  int ct = (o >> 9) & 3;
  int s  = (o >> 11) & 1;
  int k  = o >> 12;
  int c  = s * 32 + (l >> 4) * 8 + j;
  int d  = ct * 16 + (l & 15);
  wp[o] = f2bf(W[(k * 64 + c) * 64 + d]);
}

// 4-wave block, 128 rows (each wave: 32 rows = 2 x 16-row MFMA tiles).
// MODE 0: relu(conv) -> bf16. MODE 1: relu(conv+resid) -> fp32.
template <int MODE>
__global__ __launch_bounds__(256, 4) void conv_kernel(
    const ushort* __restrict__ feat,   // [N,64] bf16 bits
    const int*    __restrict__ nbr,    // [N,27]
    const ushort* __restrict__ wp,     // packed W, 27*4096 bf16
    const float*  __restrict__ resid,  // [N,64] fp32 (MODE 1)
    ushort*       __restrict__ out_bf, // MODE 0
    float*        __restrict__ out_f,  // MODE 1
    int n) {
  __shared__ __align__(16) int    sIdx[128 * KOFF];  // 128 rows x 27 offsets = 13824 B
  __shared__ __align__(16) ushort smB[2][4096];      // double-buffered W[k], 8 KB each

  const int tid  = threadIdx.x;       // 0..255
  const int lane = tid & 63;
  const int wid  = tid >> 6;          // wave 0..3
  const int quad = lane >> 4;
  const int lo   = lane & 15;
  const int mw   = blockIdx.x * 128 + wid * 32;

  // ---- Prologue stage S(0): W[0] -> smB[0] (8 chunks of 1KB, wave-uniform LDS base).
  #pragma unroll
  for (int u = 0; u < 2; ++u) {
    int c = wid * 2 + u;
    __builtin_amdgcn_global_load_lds(
        (const __attribute__((address_space(1))) void*)(wp + c * 512 + lane * 8),
        (__attribute__((address_space(3))) void*)(&smB[0][c * 512]), 16, 0, 0);
  }

  // ---- Stage block's idx rows: nbr[bid*128*27 .. +3456), contiguous, coalesced int4.
  {
    const int total = n * KOFF;
    const int g0    = blockIdx.x * (128 * KOFF);
    #pragma unroll
    for (int u = 0; u < 3; ++u) {
      int j  = tid + 256 * u;          // int4 index 0..767
      int ai = g0 + 4 * j;
      ai = ai + 4 <= total ? ai : (total - 4);   // clamp (tail block only)
      ((int4*)sIdx)[j] = *(const int4*)(nbr + ai);
    }
    if (tid < 96) {                    // int4 indices 768..863
      int j  = 768 + tid;
      int ai = g0 + 4 * j;
      ai = ai + 4 <= total ? ai : (total - 4);
      ((int4*)sIdx)[j] = *(const int4*)(nbr + ai);
    }
  }

  // Full drain once (prologue only): S(0), idx loads, ds_writes all complete.
  asm volatile("s_waitcnt vmcnt(0) lgkmcnt(0)" ::: "memory");
  __builtin_amdgcn_s_barrier();
  __builtin_amdgcn_sched_barrier(0);

  int ioff[2];
  #pragma unroll
  for (int rt = 0; rt < 2; ++rt) ioff[rt] = (wid * 32 + rt * 16 + lo) * KOFF;

  f32x4 acc[2][4];
  #pragma unroll
  for (int rt = 0; rt < 2; ++rt)
    #pragma unroll
    for (int ct = 0; ct < 4; ++ct)
      acc[rt][ct] = (f32x4)0.0f;

  // gi(0) -> issue A(0); gi(1) into gA.
  short8 aA[2][2], aB[2][2];
  int gA[2], gB[2];
  {
    int g0r[2];
    #pragma unroll
    for (int rt = 0; rt < 2; ++rt) {
      int g = sIdx[ioff[rt]];
      g0r[rt] = g < n ? g : 0;        // clamped-tail safety
    }
    #pragma unroll
    for (int rt = 0; rt < 2; ++rt) {
      const ushort* rowp = feat + g0r[rt] * 64 + quad * 8;
      aA[rt][0] = *(const short8*)(rowp);
      aA[rt][1] = *(const short8*)(rowp + 32);
    }
    #pragma unroll
    for (int rt = 0; rt < 2; ++rt) gA[rt] = sIdx[ioff[rt] + 1];
  }
  // Entry invariant for k=0: outstanding = A(0)[4]  (S(0) already complete).

  const short8* wv = (const short8*)wp;
  (void)wv;

  // One pipelined iteration. aC = data for this k (computed); aN = prefetch target for k+1.
  // giN = idx for k+1 (raw, clamped at use); gi2 = receives idx for k+2.
  auto iter = [&](int k, short8 (&aC)[2][2], short8 (&aN)[2][2],
                  int (&giN)[2], int (&gi2)[2]) {
    // 1. Issue A(k+1) (random gathers; stay in flight across the barrier).
    if (k + 1 < KOFF) {
      #pragma unroll
      for (int rt = 0; rt < 2; ++rt) {
        int g = giN[rt];
        g = g < n ? g : 0;
        const ushort* rowp = feat + g * 64 + quad * 8;
        aN[rt][0] = *(const short8*)(rowp);
        aN[rt][1] = *(const short8*)(rowp + 32);
      }
    }
    // 2. Prefetch gi(k+2) from LDS (conflict-free; clamped at use next iter).
    if (k + 2 < KOFF) {
      #pragma unroll
      for (int rt = 0; rt < 2; ++rt) gi2[rt] = sIdx[ioff[rt] + k + 2];
    }
    __builtin_amdgcn_sched_barrier(0);
    // 3. Complete A(k) and S(k); leave A(k+1) outstanding.
    if (k + 1 < KOFF) {
      asm volatile("s_waitcnt vmcnt(4)" ::: "memory");
    } else {
      asm volatile("s_waitcnt vmcnt(0)" ::: "memory");
    }
    __builtin_amdgcn_sched_barrier(0);
    // 4. Raw barrier (NO vmcnt(0) drain): all waves' stage(k) chunks are in smB[k&1];
    //    all waves finished reading smB[(k+1)&1] during iter k-1.
    __builtin_amdgcn_s_barrier();
    __builtin_amdgcn_sched_barrier(0);
    // 5. Stage S(k+1) into the other buffer (WAR-safe per the barrier above).
    if (k + 1 < KOFF) {
      #pragma unroll
      for (int u = 0; u < 2; ++u) {
        int c = wid * 2 + u;
        __builtin_amdgcn_global_load_lds(
            (const __attribute__((address_space(1))) void*)(wp + (k + 1) * 4096 + c * 512 + lane * 8),
            (__attribute__((address_space(3))) void*)(&smB[(k + 1) & 1][c * 512]), 16, 0, 0);
      }
    }
    // 6. B fragments from LDS + 16 MFMAs on aC (already resident per step 3).
    const short8* bl = (const short8*)smB[k & 1];
    short8 b[8];
    #pragma unroll
    for (int t = 0; t < 8; ++t) b[t] = bl[t * 64 + lane];
    #pragma unroll
    for (int s = 0; s < 2; ++s)
      #pragma unroll
      for (int rt = 0; rt < 2; ++rt)
        #pragma unroll
        for (int ct = 0; ct < 4; ++ct)
          acc[rt][ct] = __builtin_amdgcn_mfma_f32_16x16x32_bf16(aC[rt][s], b[s * 4 + ct], acc[rt][ct], 0, 0, 0);
  };

  // 13 pairs (k=0..25) with role swap, then the final k=26 (no prefetch, vmcnt(0)).
  #pragma unroll 1
  for (int k = 0; k < KOFF - 1; k += 2) {
    iter(k,     aA, aB, gA, gB);
    iter(k + 1, aB, aA, gB, gA);
  }
  iter(KOFF - 1, aA, aB, gA, gB);

  // Epilogue: acc[rt][ct][j] -> out[mw + rt*16 + quad*4 + j][ct*16 + lo]
  #pragma unroll
  for (int rt = 0; rt < 2; ++rt) {
    int rbase = mw + rt * 16 + quad * 4;
    #pragma unroll
    for (int ct = 0; ct < 4; ++ct) {
      int col = ct * 16 + lo;
      #pragma unroll
      for (int j = 0; j < 4; ++j) {
        int r = rbase + j;
        if (r < n) {
          float v = acc[rt][ct][j];
          if (MODE == 0) {
            v = v > 0.0f ? v : 0.0f;
            out_bf[r * 64 + col] = f2bf(v);
          } else {
            v += resid[r * 64 + col];
            v = v > 0.0f ? v : 0.0f;
            out_f[r * 64 + col] = v;
          }
        }
      }
    }
  }
}

extern "C" void kernel_launch(void* const* d_in, const int* in_sizes, int n_in,
                              void* d_out, int out_size, void* d_ws, size_t ws_size,
                              hipStream_t stream) {
  const float* x   = (const float*)d_in[0];
  const int*   nbr = (const int*)d_in[1];
  const float* W0  = (const float*)d_in[2];
  const float* W1  = (const float*)d_in[3];
  float* out = (float*)d_out;

  const int n    = NV;
  const int nc   = NV * 64;        // 9,600,000
  const int nc4  = nc / 4;         // 2,400,000
  const int wtot = KOFF * 4096;    // 110,592

  ushort* xb  = (ushort*)d_ws;
  ushort* yb  = xb + nc;
  ushort* wp0 = yb + nc;
  ushort* wp1 = wp0 + wtot;

  const int prep_units = nc4 + 2 * wtot;
  prep_kernel<<<(prep_units + 255) / 256, 256, 0, stream>>>(x, W0, W1, xb, wp0, wp1, nc4, wtot);

  const int grid = (n + 127) / 128;  // 1172 four-wave blocks
  conv_kernel<0><<<grid, 256, 0, stream>>>(xb, nbr, wp0, nullptr, yb, nullptr, n);
  conv_kernel<1><<<grid, 256, 0, stream>>>(yb, nbr, wp1, x, nullptr, out, n);
}